// Round 1
// baseline (8671.483 us; speedup 1.0000x reference)
//
#include <hip/hip_runtime.h>
#include <hip/hip_bf16.h>

#define B 4
#define N 8192
#define H 256
#define E 8192
#define M 2048
#define T_ITERS 8
#define ET 4

#define BK 16

__device__ __forceinline__ float sigmoidf_(float x) {
    return 1.0f / (1.0f + __expf(-x));
}

// inc[b, tgt, j] += sum_k h[b, src, k] * W_msg[e][j, k] + b_msg[e][j]
__global__ __launch_bounds__(256) void msg_kernel(
    const float* __restrict__ h,
    const int* __restrict__ ed0, const int* __restrict__ ed1,
    const int* __restrict__ ed2, const int* __restrict__ ed3,
    const float* __restrict__ W_msg, const float* __restrict__ b_msg,
    float* __restrict__ inc)
{
    const int tid = threadIdx.x;
    const int bz = blockIdx.z;
    const int b = bz >> 2;
    const int e = bz & 3;
    const int* ed = (e == 0) ? ed0 : (e == 1) ? ed1 : (e == 2) ? ed2 : ed3;

    const int row0 = blockIdx.x * 64;  // edge tile
    const int j0   = blockIdx.y * 64;  // output-dim tile

    __shared__ __align__(16) float As[BK][64];
    __shared__ __align__(16) float Bs[BK][64];
    __shared__ int s_src[64];
    __shared__ int s_tgt[64];

    if (tid < 64) {
        const int2 p = ((const int2*)(ed + (size_t)b * E * 2))[row0 + tid];
        s_src[tid] = p.x;
        s_tgt[tid] = p.y;
    }
    __syncthreads();

    const int tx = tid & 15, ty = tid >> 4;
    const int lr = tid & 63;          // load row within tile
    const int kb = (tid >> 6) << 2;   // k sub-offset: 0,4,8,12

    const float* Wm = W_msg + (size_t)e * H * H;

    float acc[4][4] = {};

    for (int k0 = 0; k0 < H; k0 += BK) {
        const float4 va = *(const float4*)(h + ((size_t)b * N + s_src[lr]) * H + k0 + kb);
        const float4 vb = *(const float4*)(Wm + (size_t)(j0 + lr) * H + k0 + kb);
        __syncthreads();
        As[kb + 0][lr] = va.x; As[kb + 1][lr] = va.y; As[kb + 2][lr] = va.z; As[kb + 3][lr] = va.w;
        Bs[kb + 0][lr] = vb.x; Bs[kb + 1][lr] = vb.y; Bs[kb + 2][lr] = vb.z; Bs[kb + 3][lr] = vb.w;
        __syncthreads();
        #pragma unroll
        for (int kk = 0; kk < BK; ++kk) {
            const float4 a  = *(const float4*)(&As[kk][ty << 2]);
            const float4 bb = *(const float4*)(&Bs[kk][tx << 2]);
            const float am[4] = {a.x, a.y, a.z, a.w};
            const float bn[4] = {bb.x, bb.y, bb.z, bb.w};
            #pragma unroll
            for (int mi = 0; mi < 4; ++mi)
                #pragma unroll
                for (int ni = 0; ni < 4; ++ni)
                    acc[mi][ni] += am[mi] * bn[ni];
        }
    }

    const float4 bias = *(const float4*)(b_msg + (size_t)e * H + j0 + (tx << 2));
    const float bv[4] = {bias.x, bias.y, bias.z, bias.w};
    #pragma unroll
    for (int mi = 0; mi < 4; ++mi) {
        const int tgt = s_tgt[(ty << 2) + mi];
        float* dst = inc + ((size_t)b * N + tgt) * H + j0 + (tx << 2);
        #pragma unroll
        for (int ni = 0; ni < 4; ++ni)
            atomicAdd(dst + ni, acc[mi][ni] + bv[ni]);
    }
}

// Fused GRU: computes gi = inc@W_ih^T + b_ih, gh = h@W_hh^T + b_hh (both as
// (r,z,n) triples for a 64-dim j-tile) and applies the gates, writing h_new.
__global__ __launch_bounds__(256) void gru_kernel(
    const float* __restrict__ inc, const float* __restrict__ h,
    const float* __restrict__ W_ih, const float* __restrict__ W_hh,
    const float* __restrict__ b_ih, const float* __restrict__ b_hh,
    float* __restrict__ h_new)
{
    const int tid = threadIdx.x;
    const int row0 = blockIdx.x * 64;   // flattened (B*N) node tile
    const int j0   = blockIdx.y * 64;   // hidden-dim tile

    __shared__ __align__(16) float Ai[BK][64];
    __shared__ __align__(16) float Ah[BK][64];
    __shared__ __align__(16) float Ws[6][BK][64]; // 0..2: W_ih r,z,n; 3..5: W_hh r,z,n

    const int tx = tid & 15, ty = tid >> 4;
    const int lr = tid & 63;
    const int kb = (tid >> 6) << 2;

    float acc[6][4][4] = {};

    for (int k0 = 0; k0 < H; k0 += BK) {
        const float4 va = *(const float4*)(inc + (size_t)(row0 + lr) * H + k0 + kb);
        const float4 vh = *(const float4*)(h   + (size_t)(row0 + lr) * H + k0 + kb);
        float4 w[6];
        #pragma unroll
        for (int g = 0; g < 3; ++g) {
            w[g]     = *(const float4*)(W_ih + (size_t)(g * H + j0 + lr) * H + k0 + kb);
            w[3 + g] = *(const float4*)(W_hh + (size_t)(g * H + j0 + lr) * H + k0 + kb);
        }
        __syncthreads();
        Ai[kb + 0][lr] = va.x; Ai[kb + 1][lr] = va.y; Ai[kb + 2][lr] = va.z; Ai[kb + 3][lr] = va.w;
        Ah[kb + 0][lr] = vh.x; Ah[kb + 1][lr] = vh.y; Ah[kb + 2][lr] = vh.z; Ah[kb + 3][lr] = vh.w;
        #pragma unroll
        for (int g = 0; g < 6; ++g) {
            Ws[g][kb + 0][lr] = w[g].x; Ws[g][kb + 1][lr] = w[g].y;
            Ws[g][kb + 2][lr] = w[g].z; Ws[g][kb + 3][lr] = w[g].w;
        }
        __syncthreads();
        #pragma unroll
        for (int kk = 0; kk < BK; ++kk) {
            const float4 a4 = *(const float4*)(&Ai[kk][ty << 2]);
            const float4 h4 = *(const float4*)(&Ah[kk][ty << 2]);
            const float am[4] = {a4.x, a4.y, a4.z, a4.w};
            const float hm[4] = {h4.x, h4.y, h4.z, h4.w};
            #pragma unroll
            for (int g = 0; g < 6; ++g) {
                const float4 w4 = *(const float4*)(&Ws[g][kk][tx << 2]);
                const float wn[4] = {w4.x, w4.y, w4.z, w4.w};
                #pragma unroll
                for (int mi = 0; mi < 4; ++mi) {
                    const float av = (g < 3) ? am[mi] : hm[mi];
                    #pragma unroll
                    for (int ni = 0; ni < 4; ++ni)
                        acc[g][mi][ni] += av * wn[ni];
                }
            }
        }
    }

    const int j = j0 + (tx << 2);
    const float4 bir4 = *(const float4*)(b_ih + j);
    const float4 biz4 = *(const float4*)(b_ih + H + j);
    const float4 bin4 = *(const float4*)(b_ih + 2 * H + j);
    const float4 bhr4 = *(const float4*)(b_hh + j);
    const float4 bhz4 = *(const float4*)(b_hh + H + j);
    const float4 bhn4 = *(const float4*)(b_hh + 2 * H + j);
    const float* bir = (const float*)&bir4;
    const float* biz = (const float*)&biz4;
    const float* bin = (const float*)&bin4;
    const float* bhr = (const float*)&bhr4;
    const float* bhz = (const float*)&bhz4;
    const float* bhn = (const float*)&bhn4;

    #pragma unroll
    for (int mi = 0; mi < 4; ++mi) {
        const size_t row = (size_t)row0 + (ty << 2) + mi;
        const float4 hold4 = *(const float4*)(h + row * H + j);
        const float ho[4] = {hold4.x, hold4.y, hold4.z, hold4.w};
        float o[4];
        #pragma unroll
        for (int ni = 0; ni < 4; ++ni) {
            const float gir = acc[0][mi][ni] + bir[ni];
            const float giz = acc[1][mi][ni] + biz[ni];
            const float gin = acc[2][mi][ni] + bin[ni];
            const float ghr = acc[3][mi][ni] + bhr[ni];
            const float ghz = acc[4][mi][ni] + bhz[ni];
            const float ghn = acc[5][mi][ni] + bhn[ni];
            const float r = sigmoidf_(gir + ghr);
            const float z = sigmoidf_(giz + ghz);
            const float n = tanhf(gin + r * ghn);
            o[ni] = (1.0f - z) * n + z * ho[ni];
        }
        *(float4*)(h_new + row * H + j) = make_float4(o[0], o[1], o[2], o[3]);
    }
}

// sel[b, m, :] = h[b, node_as_output[b, m], :]
__global__ __launch_bounds__(256) void sel_kernel(
    const float* __restrict__ h, const int* __restrict__ nao,
    float* __restrict__ out)
{
    const int row = blockIdx.x * 4 + (threadIdx.x >> 6);  // 0..B*M-1
    const int lane = threadIdx.x & 63;
    const int b = row >> 11;   // M = 2048
    const int idx = nao[row];
    const float4* src = (const float4*)(h + ((size_t)b * N + idx) * H);
    ((float4*)(out + (size_t)row * H))[lane] = src[lane];
}

// partial column sums of sel into gacc (for the mean over M)
__global__ __launch_bounds__(256) void gmean_kernel(
    const float* __restrict__ sel, float* __restrict__ gacc)
{
    const int b = blockIdx.x >> 4;
    const int c = blockIdx.x & 15;  // 16 chunks of 128 rows
    const int j = threadIdx.x;      // 0..255
    float s = 0.0f;
    const float* base = sel + ((size_t)b * M + (size_t)c * 128) * H + j;
    for (int m = 0; m < 128; ++m) s += base[(size_t)m * H];
    atomicAdd(&gacc[b * H + j], s);
}

__global__ __launch_bounds__(256) void final_kernel(
    const float* __restrict__ gacc, float* __restrict__ out)
{
    const int i = blockIdx.x * 256 + threadIdx.x;
    const size_t sel_sz = (size_t)B * M * H;
    if (i < B * M) {
        out[sel_sz + i] = 1.0f;  // node_mask: all true
    } else {
        const int j = i - B * M;  // 0..B*H-1
        out[sel_sz + B * M + j] = tanhf(gacc[j] * (1.0f / (float)M));
    }
}

extern "C" void kernel_launch(void* const* d_in, const int* in_sizes, int n_in,
                              void* d_out, int out_size, void* d_ws, size_t ws_size,
                              hipStream_t stream) {
    const float* emb  = (const float*)d_in[0];
    const int*   nao  = (const int*)d_in[2];
    const int*   ed0  = (const int*)d_in[3];
    const int*   ed1  = (const int*)d_in[4];
    const int*   ed2  = (const int*)d_in[5];
    const int*   ed3  = (const int*)d_in[6];
    const float* W_msg = (const float*)d_in[7];
    const float* b_msg = (const float*)d_in[8];
    const float* W_ih  = (const float*)d_in[9];
    const float* W_hh  = (const float*)d_in[10];
    const float* b_ih  = (const float*)d_in[11];
    const float* b_hh  = (const float*)d_in[12];
    float* out = (float*)d_out;

    const size_t helems = (size_t)B * N * H;
    float* hA   = (float*)d_ws;
    float* hB   = hA + helems;
    float* inc  = hB + helems;
    float* gacc = inc + helems;
    const size_t hbytes = helems * sizeof(float);

    hipMemcpyAsync(hA, emb, hbytes, hipMemcpyDeviceToDevice, stream);

    float* cur = hA;
    float* nxt = hB;
    for (int t = 0; t < T_ITERS; ++t) {
        hipMemsetAsync(inc, 0, hbytes, stream);
        msg_kernel<<<dim3(E / 64, H / 64, B * ET), 256, 0, stream>>>(
            cur, ed0, ed1, ed2, ed3, W_msg, b_msg, inc);
        gru_kernel<<<dim3((B * N) / 64, H / 64), 256, 0, stream>>>(
            inc, cur, W_ih, W_hh, b_ih, b_hh, nxt);
        float* tmp = cur; cur = nxt; nxt = tmp;
    }

    hipMemsetAsync(gacc, 0, (size_t)B * H * sizeof(float), stream);
    sel_kernel<<<dim3((B * M) / 4), 256, 0, stream>>>(cur, nao, out);
    gmean_kernel<<<dim3(B * 16), 256, 0, stream>>>(out, gacc);
    final_kernel<<<dim3((B * M + B * H) / 256), 256, 0, stream>>>(gacc, out);
}

// Round 2
// 3031.614 us; speedup vs baseline: 2.8604x; 2.8604x over previous
//
#include <hip/hip_runtime.h>

#define B 4
#define N 8192
#define H 256
#define E 8192
#define M 2048
#define T_ITERS 8
#define ET 4

typedef __bf16 bf16x8 __attribute__((ext_vector_type(8)));
typedef float f32x4 __attribute__((ext_vector_type(4)));

__device__ __forceinline__ unsigned short f2bf(float x) {
    unsigned u = __float_as_uint(x);
    u += 0x7fffu + ((u >> 16) & 1u);
    return (unsigned short)(u >> 16);
}
__device__ __forceinline__ unsigned packsplit(float x) {
    unsigned hi = f2bf(x);
    float hif = __uint_as_float(hi << 16);
    unsigned lo = f2bf(x - hif);
    return (hi << 16) | lo;
}
__device__ __forceinline__ float unpacksplit(unsigned p) {
    return __uint_as_float(p & 0xffff0000u) + __uint_as_float(p << 16);
}
__device__ __forceinline__ float fsig(float x) { return 1.0f / (1.0f + __expf(-x)); }
__device__ __forceinline__ float ftanh(float x) {
    float cx = fminf(fmaxf(x, -30.0f), 30.0f);
    float t = __expf(2.0f * cx);
    return (t - 1.0f) / (t + 1.0f);
}

// fp32 -> split bf16 hi/lo pack (also used in-place on inc)
__global__ __launch_bounds__(256) void pack_kernel(
    const float* __restrict__ src, unsigned* __restrict__ dst)
{
    const int i = blockIdx.x * 256 + threadIdx.x;
    const float4 v = ((const float4*)src)[i];
    uint4 o = { packsplit(v.x), packsplit(v.y), packsplit(v.z), packsplit(v.w) };
    ((uint4*)dst)[i] = o;
}

// fp32 -> plain bf16 (weights)
__global__ __launch_bounds__(256) void wconv_kernel(
    const float* __restrict__ src, __bf16* __restrict__ dst)
{
    const int i = blockIdx.x * 256 + threadIdx.x;
    const float4 v = ((const float4*)src)[i];
    ushort4 o = { f2bf(v.x), f2bf(v.y), f2bf(v.z), f2bf(v.w) };
    ((ushort4*)dst)[i] = o;
}

// msg: for each edge, inc[tgt] += h[src] @ W_msg[e]^T + b_msg[e]
// Block: 64 edges x full H=256 cols. 4 waves, wave w -> cols [64w, 64w+64).
// A (gathered h rows, hi/lo split) staged in LDS in 2 K-chunks of 128.
__global__ __launch_bounds__(256) void msgk(
    const unsigned* __restrict__ hpack,
    const int* __restrict__ ed0, const int* __restrict__ ed1,
    const int* __restrict__ ed2, const int* __restrict__ ed3,
    const __bf16* __restrict__ Wb, const float* __restrict__ b_msg,
    float* __restrict__ inc)
{
    const int tid = threadIdx.x;
    const int be = blockIdx.y;
    const int b = be >> 2, e = be & 3;
    const int* ed = (e == 0) ? ed0 : (e == 1) ? ed1 : (e == 2) ? ed2 : ed3;
    const int row0 = blockIdx.x * 64;

    __shared__ __bf16 sHi[64][136];  // stride 136 bf16 = 272B -> 2-way free banks
    __shared__ __bf16 sLo[64][136];
    __shared__ int s_tgt[64];

    if (tid < 64) s_tgt[tid] = ed[((size_t)b * E + row0 + tid) * 2 + 1];
    const int lrow = tid >> 2;            // 4 threads per edge row
    const int c0 = (tid & 3) * 32;        // 32 k per thread per chunk
    const int src = ed[((size_t)b * E + row0 + lrow) * 2];
    const unsigned* hrow = hpack + ((size_t)b * N + src) * H;

    const int wv = tid >> 6, ln = tid & 63, lq = ln >> 4, lm = ln & 15;
    const int jb = wv * 64;
    const __bf16* W0 = Wb + (size_t)e * H * H;

    f32x4 zero = {0.f, 0.f, 0.f, 0.f};
    f32x4 acc[4][4];
    #pragma unroll
    for (int mt = 0; mt < 4; ++mt)
        #pragma unroll
        for (int nt = 0; nt < 4; ++nt) acc[mt][nt] = zero;

    for (int ch = 0; ch < 2; ++ch) {
        __syncthreads();  // protect previous chunk's reads
        #pragma unroll
        for (int c = 0; c < 32; c += 4) {
            const uint4 u = *(const uint4*)(hrow + ch * 128 + c0 + c);
            ushort4 hi4 = { (unsigned short)(u.x >> 16), (unsigned short)(u.y >> 16),
                            (unsigned short)(u.z >> 16), (unsigned short)(u.w >> 16) };
            ushort4 lo4 = { (unsigned short)(u.x & 0xffffu), (unsigned short)(u.y & 0xffffu),
                            (unsigned short)(u.z & 0xffffu), (unsigned short)(u.w & 0xffffu) };
            *(ushort4*)&sHi[lrow][c0 + c] = hi4;
            *(ushort4*)&sLo[lrow][c0 + c] = lo4;
        }
        __syncthreads();
        #pragma unroll
        for (int ks = 0; ks < 4; ++ks) {
            const int kl = ks * 32 + lq * 8;          // k within chunk
            const int kg = ch * 128 + kl;             // global k
            bf16x8 bfr[4];
            #pragma unroll
            for (int nt = 0; nt < 4; ++nt)
                bfr[nt] = *(const bf16x8*)(W0 + (size_t)(jb + nt * 16 + lm) * H + kg);
            #pragma unroll
            for (int mt = 0; mt < 4; ++mt) {
                const bf16x8 ahi = *(const bf16x8*)&sHi[mt * 16 + lm][kl];
                const bf16x8 alo = *(const bf16x8*)&sLo[mt * 16 + lm][kl];
                #pragma unroll
                for (int nt = 0; nt < 4; ++nt) {
                    acc[mt][nt] = __builtin_amdgcn_mfma_f32_16x16x32_bf16(ahi, bfr[nt], acc[mt][nt], 0, 0, 0);
                    acc[mt][nt] = __builtin_amdgcn_mfma_f32_16x16x32_bf16(alo, bfr[nt], acc[mt][nt], 0, 0, 0);
                }
            }
        }
    }

    float bias[4];
    #pragma unroll
    for (int nt = 0; nt < 4; ++nt) bias[nt] = b_msg[e * H + jb + nt * 16 + lm];
    float* incb = inc + (size_t)b * N * H;
    #pragma unroll
    for (int mt = 0; mt < 4; ++mt) {
        #pragma unroll
        for (int r = 0; r < 4; ++r) {
            const int tgt = s_tgt[mt * 16 + lq * 4 + r];
            float* dst = incb + (size_t)tgt * H;
            #pragma unroll
            for (int nt = 0; nt < 4; ++nt)
                atomicAdd(dst + jb + nt * 16 + lm, acc[mt][nt][r] + bias[nt]);
        }
    }
}

__device__ __forceinline__ void unpack8(uint4 a, uint4 b, bf16x8& hi, bf16x8& lo) {
    union U { unsigned u[4]; bf16x8 v; } uh, ul;
    uh.u[0] = (a.x >> 16) | (a.y & 0xffff0000u);
    uh.u[1] = (a.z >> 16) | (a.w & 0xffff0000u);
    uh.u[2] = (b.x >> 16) | (b.y & 0xffff0000u);
    uh.u[3] = (b.z >> 16) | (b.w & 0xffff0000u);
    ul.u[0] = (a.x & 0xffffu) | (a.y << 16);
    ul.u[1] = (a.z & 0xffffu) | (a.w << 16);
    ul.u[2] = (b.x & 0xffffu) | (b.y << 16);
    ul.u[3] = (b.z & 0xffffu) | (b.w << 16);
    hi = uh.v; lo = ul.v;
}

// Fused GRU via MFMA. Block: 64 rows x 64 j. Wave w -> rows [16w,16w+16),
// all 6 gate planes. No LDS: A frags read directly from packed global rows.
__global__ __launch_bounds__(256) void gruk(
    const unsigned* __restrict__ ipack, const unsigned* __restrict__ hpack,
    const __bf16* __restrict__ Wihb, const __bf16* __restrict__ Whhb,
    const float* __restrict__ b_ih, const float* __restrict__ b_hh,
    unsigned* __restrict__ hpack_new)
{
    const int tid = threadIdx.x;
    const int wv = tid >> 6, ln = tid & 63, lq = ln >> 4, lm = ln & 15;
    const size_t rowbase = (size_t)blockIdx.x * 64 + wv * 16;
    const int J0 = blockIdx.y * 64;

    const unsigned* xrow = ipack + (rowbase + lm) * H;
    const unsigned* hrow = hpack + (rowbase + lm) * H;

    f32x4 zero = {0.f, 0.f, 0.f, 0.f};
    f32x4 acc[6][4];
    #pragma unroll
    for (int g = 0; g < 6; ++g)
        #pragma unroll
        for (int nt = 0; nt < 4; ++nt) acc[g][nt] = zero;

    for (int ks = 0; ks < 8; ++ks) {
        const int k = ks * 32 + lq * 8;
        const uint4 px0 = *(const uint4*)(xrow + k);
        const uint4 px1 = *(const uint4*)(xrow + k + 4);
        const uint4 ph0 = *(const uint4*)(hrow + k);
        const uint4 ph1 = *(const uint4*)(hrow + k + 4);
        bf16x8 xhi, xlo, hhi, hlo;
        unpack8(px0, px1, xhi, xlo);
        unpack8(ph0, ph1, hhi, hlo);
        #pragma unroll
        for (int g = 0; g < 6; ++g) {
            const __bf16* Wg = (g < 3) ? (Wihb + (size_t)g * H * H)
                                       : (Whhb + (size_t)(g - 3) * H * H);
            const bf16x8 ahi = (g < 3) ? xhi : hhi;
            const bf16x8 alo = (g < 3) ? xlo : hlo;
            #pragma unroll
            for (int nt = 0; nt < 4; ++nt) {
                const bf16x8 bf = *(const bf16x8*)(Wg + (size_t)(J0 + nt * 16 + lm) * H + k);
                acc[g][nt] = __builtin_amdgcn_mfma_f32_16x16x32_bf16(ahi, bf, acc[g][nt], 0, 0, 0);
                acc[g][nt] = __builtin_amdgcn_mfma_f32_16x16x32_bf16(alo, bf, acc[g][nt], 0, 0, 0);
            }
        }
    }

    #pragma unroll
    for (int nt = 0; nt < 4; ++nt) {
        const int col = J0 + nt * 16 + lm;
        const float bi_r = b_ih[col], bi_z = b_ih[H + col], bi_n = b_ih[2 * H + col];
        const float bh_r = b_hh[col], bh_z = b_hh[H + col], bh_n = b_hh[2 * H + col];
        #pragma unroll
        for (int r = 0; r < 4; ++r) {
            const size_t row = rowbase + lq * 4 + r;
            const float hold = unpacksplit(hpack[row * H + col]);
            const float rg = fsig(acc[0][nt][r] + bi_r + acc[3][nt][r] + bh_r);
            const float zg = fsig(acc[1][nt][r] + bi_z + acc[4][nt][r] + bh_z);
            const float ng = ftanh(acc[2][nt][r] + bi_n + rg * (acc[5][nt][r] + bh_n));
            const float o = (1.0f - zg) * ng + zg * hold;
            hpack_new[row * H + col] = packsplit(o);
        }
    }
}

// sel[b, m, :] = h[b, node_as_output[b, m], :]  (unpack split-bf16 -> fp32)
__global__ __launch_bounds__(256) void sel_kernel(
    const unsigned* __restrict__ hpack, const int* __restrict__ nao,
    float* __restrict__ out)
{
    const int row = blockIdx.x * 4 + (threadIdx.x >> 6);
    const int lane = threadIdx.x & 63;
    const int b = row >> 11;  // M = 2048
    const int idx = nao[row];
    const uint4 p = ((const uint4*)(hpack + ((size_t)b * N + idx) * H))[lane];
    float4 v = { unpacksplit(p.x), unpacksplit(p.y), unpacksplit(p.z), unpacksplit(p.w) };
    ((float4*)(out + (size_t)row * H))[lane] = v;
}

__global__ __launch_bounds__(256) void gmean_kernel(
    const float* __restrict__ sel, float* __restrict__ gacc)
{
    const int b = blockIdx.x >> 4;
    const int c = blockIdx.x & 15;
    const int j = threadIdx.x;
    float s = 0.0f;
    const float* base = sel + ((size_t)b * M + (size_t)c * 128) * H + j;
    for (int m = 0; m < 128; ++m) s += base[(size_t)m * H];
    atomicAdd(&gacc[b * H + j], s);
}

__global__ __launch_bounds__(256) void final_kernel(
    const float* __restrict__ gacc, float* __restrict__ out)
{
    const int i = blockIdx.x * 256 + threadIdx.x;
    const size_t sel_sz = (size_t)B * M * H;
    if (i < B * M) {
        out[sel_sz + i] = 1.0f;
    } else {
        const int j = i - B * M;
        out[sel_sz + B * M + j] = tanhf(gacc[j] * (1.0f / (float)M));
    }
}

extern "C" void kernel_launch(void* const* d_in, const int* in_sizes, int n_in,
                              void* d_out, int out_size, void* d_ws, size_t ws_size,
                              hipStream_t stream) {
    const float* emb  = (const float*)d_in[0];
    const int*   nao  = (const int*)d_in[2];
    const int*   ed0  = (const int*)d_in[3];
    const int*   ed1  = (const int*)d_in[4];
    const int*   ed2  = (const int*)d_in[5];
    const int*   ed3  = (const int*)d_in[6];
    const float* W_msg = (const float*)d_in[7];
    const float* b_msg = (const float*)d_in[8];
    const float* W_ih  = (const float*)d_in[9];
    const float* W_hh  = (const float*)d_in[10];
    const float* b_ih  = (const float*)d_in[11];
    const float* b_hh  = (const float*)d_in[12];
    float* out = (float*)d_out;

    const size_t helems = (size_t)B * N * H;      // 8.4M
    const size_t hbytes = helems * sizeof(unsigned);

    unsigned* hpA  = (unsigned*)d_ws;
    unsigned* hpB  = hpA + helems;
    float*    inc  = (float*)(hpB + helems);
    unsigned* ipk  = (unsigned*)inc;              // packed in place
    __bf16*   Wmb  = (__bf16*)((char*)inc + hbytes);
    __bf16*   Wihb = Wmb + (size_t)ET * H * H;
    __bf16*   Whhb = Wihb + (size_t)3 * H * H;
    float*    gacc = (float*)Wmb;                 // alias: used only after iters

    wconv_kernel<<<dim3(ET * H * H / 4 / 256), 256, 0, stream>>>(W_msg, Wmb);
    wconv_kernel<<<dim3(3 * H * H / 4 / 256), 256, 0, stream>>>(W_ih, Wihb);
    wconv_kernel<<<dim3(3 * H * H / 4 / 256), 256, 0, stream>>>(W_hh, Whhb);
    pack_kernel<<<dim3(helems / 4 / 256), 256, 0, stream>>>(emb, hpA);

    unsigned* cur = hpA;
    unsigned* nxt = hpB;
    for (int t = 0; t < T_ITERS; ++t) {
        hipMemsetAsync(inc, 0, hbytes, stream);
        msgk<<<dim3(E / 64, B * ET), 256, 0, stream>>>(
            cur, ed0, ed1, ed2, ed3, Wmb, b_msg, inc);
        pack_kernel<<<dim3(helems / 4 / 256), 256, 0, stream>>>(inc, ipk);
        gruk<<<dim3(B * N / 64, H / 64), 256, 0, stream>>>(
            ipk, cur, Wihb, Whhb, b_ih, b_hh, nxt);
        unsigned* tmp = cur; cur = nxt; nxt = tmp;
    }

    hipMemsetAsync(gacc, 0, (size_t)B * H * sizeof(float), stream);
    sel_kernel<<<dim3(B * M / 4), 256, 0, stream>>>(cur, nao, out);
    gmean_kernel<<<dim3(B * 16), 256, 0, stream>>>(out, gacc);
    final_kernel<<<dim3((B * M + B * H) / 256), 256, 0, stream>>>(gacc, out);
}